// Round 13
// baseline (49.995 us; speedup 1.0000x reference)
//
#include <hip/hip_runtime.h>
#include <math.h>

#define TPB 128

constexpr int Bn    = 131072;
constexpr float LOG2E = 1.4426950408889634f;

typedef float v2f __attribute__((ext_vector_type(2)));

__global__ __launch_bounds__(TPB)
void gat_ppo_kernel(const float* __restrict__ xg,
                    const float* __restrict__ adjg,
                    const float* __restrict__ Wg,
                    const float* __restrict__ ahg,
                    const float* __restrict__ wog,
                    const float* __restrict__ aog,
                    const float* __restrict__ muWg,
                    const float* __restrict__ mubg,
                    const float* __restrict__ sgWg,
                    const float* __restrict__ sgbg,
                    const float* __restrict__ vWg,
                    const float* __restrict__ vbg,
                    float* __restrict__ outg)
{
    // Residency probe: R5-proven structure (sequential heads, wave-local
    // 3.2KB tile, direct x loads, no barriers) at TPB=128 / 8192 blocks.
    // Caps: thread-slots 16 blocks/CU, LDS 25 blocks/CU -> 32 waves/CU
    // possible if the per-CU workgroup-slot limit is >= 16.
    __shared__ float4 tile[2 * 200];   // 6.4 KB

    const int lb = threadIdx.x;
    const int w  = lb >> 6;                 // wave id in block (0..1)
    const int g  = (lb & 63) >> 3;          // graph within wave
    const int n  = lb & 7;                  // node id
    const size_t t = (size_t)blockIdx.x * TPB + lb;   // global row = b*8 + n

    float4* wt4 = tile + w * 200;

    // ---- adj row -> 8-bit mask ----
    unsigned amask;
    {
        const float4* a4 = (const float4*)(adjg) + t * 2;
        float4 a0 = a4[0], a1 = a4[1];
        amask =  (unsigned)(a0.x > 0.0f)
              | ((unsigned)(a0.y > 0.0f) << 1)
              | ((unsigned)(a0.z > 0.0f) << 2)
              | ((unsigned)(a0.w > 0.0f) << 3)
              | ((unsigned)(a1.x > 0.0f) << 4)
              | ((unsigned)(a1.y > 0.0f) << 5)
              | ((unsigned)(a1.z > 0.0f) << 6)
              | ((unsigned)(a1.w > 0.0f) << 7);
    }

    // ---- x row: direct per-lane loads ----
    float x[30];
    {
        const float2* xr = (const float2*)(xg + t * 30);
        #pragma unroll
        for (int k = 0; k < 15; ++k) {
            float2 v = xr[k];
            x[2 * k] = v.x; x[2 * k + 1] = v.y;
        }
    }

    // ---- per-head: Wh row (pk-FMA) -> LDS tile -> softmax -> aggregate ----
    const v2f* Wp = (const v2f*)Wg;
    float wh2 = 0.0f;

    #pragma unroll
    for (int h = 0; h < 3; ++h) {
        v2f acc[4];
        #pragma unroll
        for (int o2 = 0; o2 < 4; ++o2) acc[o2] = (v2f){0.0f, 0.0f};
        #pragma unroll
        for (int f = 0; f < 30; ++f) {
            v2f xf = (v2f){x[f], x[f]};
            #pragma unroll
            for (int o2 = 0; o2 < 4; ++o2)
                acc[o2] = __builtin_elementwise_fma(xf, Wp[h * 120 + f * 4 + o2], acc[o2]);
        }

        // f1, f2 scores (log2 domain)
        float s1 = 0.0f, s2 = 0.0f;
        #pragma unroll
        for (int o2 = 0; o2 < 4; ++o2) {
            s1 = fmaf(acc[o2].x, ahg[h * 16 + 2 * o2],     s1);
            s1 = fmaf(acc[o2].y, ahg[h * 16 + 2 * o2 + 1], s1);
            s2 = fmaf(acc[o2].x, ahg[h * 16 + 8 + 2 * o2],     s2);
            s2 = fmaf(acc[o2].y, ahg[h * 16 + 8 + 2 * o2 + 1], s2);
        }
        float f1h = s1 * LOG2E;
        float f2h = s2 * LOG2E;

        // publish own Wh row to the wave-local tile (2 x b128)
        wt4[g * 25 + n * 3]     = (float4){acc[0].x, acc[0].y, acc[1].x, acc[1].y};
        wt4[g * 25 + n * 3 + 1] = (float4){acc[2].x, acc[2].y, acc[3].x, acc[3].y};

        // masked softmax weights, unnormalized (no max pass, exp2)
        float p[8];
        float s = 0.0f;
        #pragma unroll
        for (int m = 0; m < 8; ++m) {
            float ev = f1h + __shfl(f2h, m, 8);
            ev = fmaxf(ev, 0.2f * ev);                    // leaky (log2-scaled)
            float pe = ((amask >> m) & 1u) ? __builtin_amdgcn_exp2f(ev) : 0.0f;
            p[m] = pe; s += pe;
        }

        // aggregate unnormalized; divide once at the end
        v2f hacc[4];
        #pragma unroll
        for (int o2 = 0; o2 < 4; ++o2) hacc[o2] = (v2f){0.0f, 0.0f};
        #pragma unroll
        for (int m = 0; m < 8; ++m) {
            float4 lo = wt4[g * 25 + m * 3];
            float4 hi = wt4[g * 25 + m * 3 + 1];
            v2f av = (v2f){p[m], p[m]};
            hacc[0] = __builtin_elementwise_fma(av, (v2f){lo.x, lo.y}, hacc[0]);
            hacc[1] = __builtin_elementwise_fma(av, (v2f){lo.z, lo.w}, hacc[1]);
            hacc[2] = __builtin_elementwise_fma(av, (v2f){hi.x, hi.y}, hacc[2]);
            hacc[3] = __builtin_elementwise_fma(av, (v2f){hi.z, hi.w}, hacc[3]);
        }
        float rs = 1.0f / s;
        #pragma unroll
        for (int o2 = 0; o2 < 4; ++o2) {
            #pragma unroll
            for (int j = 0; j < 2; ++j) {
                float hv = hacc[o2][j] * rs;
                hv = (hv > 0.0f) ? hv : (__expf(hv) - 1.0f);   // elu
                wh2 = fmaf(hv, wog[h * 8 + 2 * o2 + j], wh2);  // h @ W_out
            }
        }
    }

    // ---- second GAT layer on Wh2 (log2 domain, no max pass, deferred norm) ----
    const float a0c = aog[0] * LOG2E, a1c = aog[1] * LOG2E;
    float wh2a[8];
    #pragma unroll
    for (int m = 0; m < 8; ++m) wh2a[m] = __shfl(wh2, m, 8);

    float g1 = a0c * wh2;
    float s2s = 0.0f;
    float og = 0.0f;
    #pragma unroll
    for (int m = 0; m < 8; ++m) {
        float ev = fmaf(a1c, wh2a[m], g1);
        ev = fmaxf(ev, 0.2f * ev);
        float pe = ((amask >> m) & 1u) ? __builtin_amdgcn_exp2f(ev) : 0.0f;
        s2s += pe;
        og = fmaf(pe, wh2a[m], og);
    }
    og /= s2s;
    float g2v = (og > 0.0f) ? og : (__expf(og) - 1.0f);   // elu -> g[b][n]

    // ---- MLP heads: mu, sigma (per node), value (per batch) ----
    v2f gp[4];
    #pragma unroll
    for (int m = 0; m < 4; ++m)
        gp[m] = (v2f){__shfl(g2v, 2 * m, 8), __shfl(g2v, 2 * m + 1, 8)};

    const v2f* muWp = (const v2f*)muWg;
    const v2f* sgWp = (const v2f*)sgWg;
    const v2f* vWp  = (const v2f*)vWg;
    v2f ma = (v2f){0.0f, 0.0f}, sa = (v2f){0.0f, 0.0f}, va = (v2f){0.0f, 0.0f};
    #pragma unroll
    for (int k = 0; k < 4; ++k) {
        ma = __builtin_elementwise_fma(gp[k], muWp[n * 4 + k], ma);
        sa = __builtin_elementwise_fma(gp[k], sgWp[n * 4 + k], sa);
        va = __builtin_elementwise_fma(gp[k], vWp[k],          va);
    }
    float mu = ma.x + ma.y + mubg[n];
    float sg = sa.x + sa.y + sgbg[n];
    float vv = va.x + va.y + vbg[0];

    mu = 1.0f / (1.0f + __expf(-mu));                               // sigmoid
    sg = fmaxf(sg, 0.0f) + log1pf(__expf(-fabsf(sg))) + 0.001f;     // softplus + 1e-3

    outg[t]          = mu;
    outg[Bn * 8 + t] = sg;
    if (n == 0) outg[Bn * 16 + (t >> 3)] = vv;
}

extern "C" void kernel_launch(void* const* d_in, const int* in_sizes, int n_in,
                              void* d_out, int out_size, void* d_ws, size_t ws_size,
                              hipStream_t stream) {
    const float* xg   = (const float*)d_in[0];
    const float* adjg = (const float*)d_in[1];
    const float* Wg   = (const float*)d_in[2];
    const float* ahg  = (const float*)d_in[3];
    const float* wog  = (const float*)d_in[4];
    const float* aog  = (const float*)d_in[5];
    const float* muW  = (const float*)d_in[6];
    const float* mub  = (const float*)d_in[7];
    const float* sgW  = (const float*)d_in[8];
    const float* sgb  = (const float*)d_in[9];
    const float* vW   = (const float*)d_in[10];
    const float* vb   = (const float*)d_in[11];
    float* outg = (float*)d_out;

    dim3 grid(Bn * 8 / TPB);  // 8192 blocks of 128 threads (2 waves/block)
    gat_ppo_kernel<<<grid, TPB, 0, stream>>>(xg, adjg, Wg, ahg, wog, aog,
                                             muW, mub, sgW, sgb, vW, vb, outg);
}